// Round 7
// baseline (440.195 us; speedup 1.0000x reference)
//
#include <hip/hip_runtime.h>
#include <stdint.h>

// SingleStreamBlock on MI355X. fp32 in/out (per reference), bf16 MFMA compute.
// B=2 L=2048 HID=1024 NH=16 HD=64 MLP=4096.

#define HID  1024
#define NH   16
#define HD   64
#define MLP  4096
#define D1   7168   // 3*HID + MLP
#define DQKV 3072
#define DCAT 2048
#define BB   2
#define LL   2048
#define TOK  4096

typedef __attribute__((ext_vector_type(8))) short    bf16x8;
typedef __attribute__((ext_vector_type(4))) float    f32x4;
typedef __attribute__((ext_vector_type(4))) unsigned int u32x4;

__device__ __forceinline__ float b2f(unsigned short u) {
    unsigned int v = ((unsigned int)u) << 16;
    float f; __builtin_memcpy(&f, &v, 4); return f;
}
__device__ __forceinline__ unsigned short f2b(float f) {   // RNE
    unsigned int v; __builtin_memcpy(&v, &f, 4);
    unsigned int r = (v + 0x7FFFu + ((v >> 16) & 1u)) >> 16;
    return (unsigned short)r;
}
// cheap round-to-nearest pack of 2 floats -> 2 bf16 in a u32
__device__ __forceinline__ unsigned int pkbf2(float a, float b) {
    unsigned int ua, ub;
    __builtin_memcpy(&ua, &a, 4); __builtin_memcpy(&ub, &b, 4);
    return ((ua + 0x8000u) >> 16) | ((ub + 0x8000u) & 0xFFFF0000u);
}
// async global->LDS, 16 B per lane (dest is wave-uniform base + lane*16)
__device__ __forceinline__ void gl_lds16(const unsigned short* g, unsigned short* l) {
    __builtin_amdgcn_global_load_lds(
        (const __attribute__((address_space(1))) unsigned int*)(g),
        (__attribute__((address_space(3))) unsigned int*)(l), 16, 0, 0);
}

// ---------------- transpose+cast: fp32 (R x C) -> bf16 (C x R) ----------------
__global__ void k_transpose_cvt(const float* __restrict__ in,
                                unsigned short* __restrict__ out, int R, int C) {
    __shared__ float tile[32][33];
    int bx = blockIdx.x, by = blockIdx.y;
    int tx = threadIdx.x, ty = threadIdx.y;   // (32,8)
    #pragma unroll
    for (int i = 0; i < 4; i++) {
        int r = by * 32 + ty + i * 8;
        int c = bx * 32 + tx;
        tile[ty + i * 8][tx] = in[(size_t)r * C + c];
    }
    __syncthreads();
    #pragma unroll
    for (int i = 0; i < 4; i++) {
        int ro = bx * 32 + ty + i * 8;   // original col
        int co = by * 32 + tx;           // original row
        out[(size_t)ro * R + co] = f2b(tile[tx][ty + i * 8]);
    }
}

// ---------------- V transpose: h[:, 2048+h*64+d] -> vT[(b,h,d)][l] bf16 ----------------
__global__ void k_vt(const unsigned short* __restrict__ h,
                     unsigned short* __restrict__ vT) {
    __shared__ unsigned short tile[32][33];
    int l0 = blockIdx.x * 32;
    int d0 = (blockIdx.y & 1) * 32;
    int bh = blockIdx.y >> 1;
    int b = bh >> 4, hh = bh & 15;
    int tx = threadIdx.x, ty = threadIdx.y;   // (32,8)
    const unsigned short* src = h + ((size_t)(b * LL) + l0) * D1 + 2 * HID + hh * HD + d0;
    #pragma unroll
    for (int i = 0; i < 4; i++)
        tile[ty + i * 8][tx] = src[(size_t)(ty + i * 8) * D1 + tx];
    __syncthreads();
    unsigned short* dst = vT + ((size_t)(b * NH + hh) * HD + d0) * LL + l0;
    #pragma unroll
    for (int i = 0; i < 4; i++)
        dst[(size_t)(ty + i * 8) * LL + tx] = tile[tx][ty + i * 8];
}

// ---------------- mod = silu(vec) @ w_mod + b_mod (fp32) ----------------
__global__ void k_mod(const float* __restrict__ vec,
                      const float* __restrict__ w_mod,
                      const float* __restrict__ b_mod,
                      float* __restrict__ mod) {
    __shared__ float sv[HID];
    __shared__ float red[8][32];
    int b = blockIdx.y, t = threadIdx.x;
    for (int j = t; j < HID; j += 256) {
        float v = vec[b * HID + j];
        sv[j] = v / (1.0f + __expf(-v));
    }
    __syncthreads();
    int n0 = blockIdx.x * 32;
    int on = t & 31, ks = t >> 5;
    float acc = 0.f;
    const float* wp = w_mod + (size_t)(ks * 128) * 3072 + n0 + on;
    #pragma unroll 4
    for (int k = 0; k < 128; k++) acc += sv[ks * 128 + k] * wp[(size_t)k * 3072];
    red[ks][on] = acc;
    __syncthreads();
    if (t < 32) {
        float s = 0.f;
        #pragma unroll
        for (int i = 0; i < 8; i++) s += red[i][t];
        mod[b * 3072 + n0 + t] = s + b_mod[n0 + t];
    }
}

// ---------------- x_mod = (1+scale)*layernorm(x) + shift, bf16 out ----------------
__global__ void k_lnmod(const float* __restrict__ x,
                        const float* __restrict__ mod,
                        unsigned short* __restrict__ xmod) {
    int tok = blockIdx.x;
    int t = threadIdx.x;
    int b = tok >> 11;
    float4 v4 = *(const float4*)(x + (size_t)tok * HID + t * 4);
    float v0 = v4.x, v1 = v4.y, v2 = v4.z, v3 = v4.w;
    float s  = v0 + v1 + v2 + v3;
    float sq = v0*v0 + v1*v1 + v2*v2 + v3*v3;
    for (int off = 1; off < 64; off <<= 1) {
        s  += __shfl_xor(s,  off);
        sq += __shfl_xor(sq, off);
    }
    __shared__ float ls[4], lq[4];
    int w = t >> 6;
    if ((t & 63) == 0) { ls[w] = s; lq[w] = sq; }
    __syncthreads();
    s  = ls[0] + ls[1] + ls[2] + ls[3];
    sq = lq[0] + lq[1] + lq[2] + lq[3];
    float mean = s * (1.0f / HID);
    float var  = sq * (1.0f / HID) - mean * mean;
    float rstd = rsqrtf(var + 1e-6f);
    const float* mb = mod + b * 3072;
    float y[4] = {v0, v1, v2, v3};
    unsigned short r[4];
    #pragma unroll
    for (int j = 0; j < 4; j++) {
        int col = t * 4 + j;
        float nval = (y[j] - mean) * rstd;
        r[j] = f2b((1.0f + mb[1024 + col]) * nval + mb[col]);
    }
    unsigned int o0 = (unsigned int)r[0] | ((unsigned int)r[1] << 16);
    unsigned int o1 = (unsigned int)r[2] | ((unsigned int)r[3] << 16);
    *(uint2*)(xmod + (size_t)tok * HID + t * 4) = make_uint2(o0, o1);
}

// ---------------- MFMA GEMM (BK=64, global_load_lds, XOR-8 swizzle) ----------------
// C[M,N] = A[M,K](bf16) @ Bt[N,K](bf16)^T + bias(f32)
// Operand-swapped MFMA (D = C^T fragments): lane holds 4 consecutive N cols ->
// vectorized epilogue stores.
// EPI: 0 = store bf16; 1 = tanh -> bf16; 2 = out(f32) = x + gate*(acc+bias)
// EPI: 3 = split-K fp32 partial (no bias), gridDim.z splits K
template<int EPI>
__global__ __launch_bounds__(256) void k_gemm(
    const unsigned short* __restrict__ A, int lda,
    const unsigned short* __restrict__ Bt, int ldb,
    const float* __restrict__ bias,
    unsigned short* __restrict__ C, float* __restrict__ Cf, int ldc,
    int K,
    const float* __restrict__ xin,
    const float* __restrict__ mod) {
    __shared__ alignas(16) unsigned short As[128 * 64];
    __shared__ alignas(16) unsigned short Bs[128 * 64];
    int t = threadIdx.x;
    // panel swizzle: 8-wide bn panels, bn fastest within panel (L2/L3 locality)
    int bi = blockIdx.y * gridDim.x + blockIdx.x;
    int span = gridDim.x * 8;
    int pid = bi / span, rem = bi % span;
    int bn = pid * 8 + (rem & 7);
    int bm = rem >> 3;
    int lane = t & 63, wave = t >> 6;
    int wm = (wave >> 1) * 64, wn = (wave & 1) * 64;
    int ln = lane & 15, quad = lane >> 4;
    int ln7 = ln & 7;

    f32x4 acc[4][4];
    #pragma unroll
    for (int i = 0; i < 4; i++)
        #pragma unroll
        for (int j = 0; j < 4; j++) acc[i][j] = {0.f, 0.f, 0.f, 0.f};

    int sr  = t >> 3;                    // staging row 0..31 (per 32-row group)
    int scg = (t & 7) ^ (sr & 7);        // global chunk fetched by this lane
    const unsigned short* Ab = A  + (size_t)(bm * 128) * lda;
    const unsigned short* Bb = Bt + (size_t)(bn * 128) * ldb;

    int ksplit = K / gridDim.z;
    int kbeg = blockIdx.z * ksplit, kend = kbeg + ksplit;

    for (int k0 = kbeg; k0 < kend; k0 += 64) {
        __syncthreads();
        #pragma unroll
        for (int c = 0; c < 4; c++) {
            gl_lds16(Ab + (size_t)(c * 32 + sr) * lda + k0 + scg * 8, &As[c * 2048 + t * 8]);
            gl_lds16(Bb + (size_t)(c * 32 + sr) * ldb + k0 + scg * 8, &Bs[c * 2048 + t * 8]);
        }
        __syncthreads();
        #pragma unroll
        for (int ks = 0; ks < 2; ks++) {
            int slot = ((ks * 4 + quad) ^ ln7) * 8;
            bf16x8 af[4], bfr[4];
            #pragma unroll
            for (int i = 0; i < 4; i++)
                af[i] = *(const bf16x8*)(&As[(wm + i * 16 + ln) * 64 + slot]);
            #pragma unroll
            for (int j = 0; j < 4; j++)
                bfr[j] = *(const bf16x8*)(&Bs[(wn + j * 16 + ln) * 64 + slot]);
            #pragma unroll
            for (int i = 0; i < 4; i++)
                #pragma unroll
                for (int j = 0; j < 4; j++)
                    // operand-swapped: D[row=n][col=m]
                    acc[i][j] = __builtin_amdgcn_mfma_f32_16x16x32_bf16(bfr[j], af[i], acc[i][j], 0, 0, 0);
        }
    }

    #pragma unroll
    for (int i = 0; i < 4; i++) {
        #pragma unroll
        for (int j = 0; j < 4; j++) {
            int trow = bm * 128 + wm + i * 16 + ln;        // M row (token)
            int ncol = bn * 128 + wn + j * 16 + quad * 4;  // N col base, 4 consecutive
            f32x4 a = acc[i][j];
            if (EPI == 3) {
                float4 o = make_float4(a[0], a[1], a[2], a[3]);
                *(float4*)(&Cf[((size_t)blockIdx.z * TOK + trow) * ldc + ncol]) = o;
            } else {
                float4 bv = *(const float4*)(bias + ncol);
                float v0 = a[0] + bv.x, v1 = a[1] + bv.y, v2 = a[2] + bv.z, v3 = a[3] + bv.w;
                if (EPI == 1) { v0 = tanhf(v0); v1 = tanhf(v1); v2 = tanhf(v2); v3 = tanhf(v3); }
                if (EPI == 0 || EPI == 1) {
                    *(uint2*)(&C[(size_t)trow * ldc + ncol]) =
                        make_uint2(pkbf2(v0, v1), pkbf2(v2, v3));
                } else {
                    int b = trow >> 11;
                    float4 gv = *(const float4*)(mod + b * 3072 + 2048 + ncol);
                    float4 xv = *(const float4*)(xin + (size_t)trow * HID + ncol);
                    float4 o = make_float4(xv.x + gv.x * v0, xv.y + gv.y * v1,
                                           xv.z + gv.z * v2, xv.w + gv.w * v3);
                    *(float4*)(&Cf[(size_t)trow * ldc + ncol]) = o;
                }
            }
        }
    }
}

// ---------------- split-K reduce 1: cat[:,1024:] = tanh(p0+p1+bias) ----------------
__global__ __launch_bounds__(256) void k_red1(const float* __restrict__ part,
                                              const float* __restrict__ bias,
                                              unsigned short* __restrict__ cat) {
    int idx = blockIdx.x * 256 + threadIdx.x;
    int row = idx >> 8;
    int c4  = (idx & 255) * 4;
    float4 p0 = *(const float4*)(part + (size_t)row * HID + c4);
    float4 p1 = *(const float4*)(part + ((size_t)TOK + row) * HID + c4);
    float4 bv = *(const float4*)(bias + c4);
    float a0 = tanhf(p0.x + p1.x + bv.x);
    float a1 = tanhf(p0.y + p1.y + bv.y);
    float a2 = tanhf(p0.z + p1.z + bv.z);
    float a3 = tanhf(p0.w + p1.w + bv.w);
    *(uint2*)(&cat[(size_t)row * DCAT + HID + c4]) =
        make_uint2(pkbf2(a0, a1), pkbf2(a2, a3));
}

// ---------------- split-K reduce 2: out = x + gate*(p0+p1+bias) (fp32) ----------------
__global__ __launch_bounds__(256) void k_red2(const float* __restrict__ part,
                                              const float* __restrict__ bias,
                                              const float* __restrict__ x,
                                              const float* __restrict__ mod,
                                              float* __restrict__ out) {
    int idx = blockIdx.x * 256 + threadIdx.x;
    int row = idx >> 8;
    int c4  = (idx & 255) * 4;
    int b = row >> 11;
    float4 p0 = *(const float4*)(part + (size_t)row * HID + c4);
    float4 p1 = *(const float4*)(part + ((size_t)TOK + row) * HID + c4);
    float4 bv = *(const float4*)(bias + c4);
    float4 gv = *(const float4*)(mod + b * 3072 + 2048 + c4);
    float4 xv = *(const float4*)(x + (size_t)row * HID + c4);
    float4 o;
    o.x = xv.x + gv.x * (p0.x + p1.x + bv.x);
    o.y = xv.y + gv.y * (p0.y + p1.y + bv.y);
    o.z = xv.z + gv.z * (p0.z + p1.z + bv.z);
    o.w = xv.w + gv.w * (p0.w + p1.w + bv.w);
    *(float4*)(out + (size_t)row * HID + c4) = o;
}

// ---------------- per-head RMSNorm + RoPE on q,k (in place in h, bf16) ----------------
// q additionally pre-scaled by 0.125*log2(e) so attention softmax runs in exp2 domain.
__global__ void k_qkrope(unsigned short* __restrict__ h,
                         const float* __restrict__ pe,
                         const float* __restrict__ q_scale,
                         const float* __restrict__ k_scale) {
    int tok = blockIdx.x;
    int l = tok & (LL - 1);
    int t = threadIdx.x;
    int lane = t & 63, wave = t >> 6;
    int hh = wave * 4 + (lane >> 4);      // head 0..15
    int d0 = (lane & 15) * 4;             // 4 dims = 2 rope pairs
    unsigned short* row = h + (size_t)tok * D1;
    int i0 = d0 >> 1;
    const float* peb = pe + ((size_t)l * 32 + i0) * 4;
    float4 e0 = *(const float4*)(peb);
    float4 e1 = *(const float4*)(peb + 4);
    #pragma unroll
    for (int qk = 0; qk < 2; qk++) {
        unsigned short* p = row + qk * HID + hh * HD + d0;
        const float* sc = (qk == 0 ? q_scale : k_scale) + d0;
        uint2 qv = *(const uint2*)p;
        float v0 = b2f((unsigned short)(qv.x & 0xFFFF)), v1 = b2f((unsigned short)(qv.x >> 16));
        float v2 = b2f((unsigned short)(qv.y & 0xFFFF)), v3 = b2f((unsigned short)(qv.y >> 16));
        float ssq = v0*v0 + v1*v1 + v2*v2 + v3*v3;
        ssq += __shfl_xor(ssq, 1, 16);
        ssq += __shfl_xor(ssq, 2, 16);
        ssq += __shfl_xor(ssq, 4, 16);
        ssq += __shfl_xor(ssq, 8, 16);
        float rr = rsqrtf(ssq * (1.0f / HD) + 1e-6f);
        if (qk == 0) rr *= 0.18033688011112042f;   // 0.125 * log2(e)
        v0 *= rr * sc[0];
        v1 *= rr * sc[1];
        v2 *= rr * sc[2];
        v3 *= rr * sc[3];
        float o0 = e0.x*v0 + e0.y*v1;
        float o1 = e0.z*v0 + e0.w*v1;
        float o2 = e1.x*v2 + e1.y*v3;
        float o3 = e1.z*v2 + e1.w*v3;
        *(uint2*)p = make_uint2(pkbf2(o0, o1), pkbf2(o2, o3));
    }
}

// ---------------- MFMA flash attention (exp2 domain, 64 Q-rows/block) ----------------
// K and V^T staged with global_load_lds into unpadded [64][64] + XOR-8 swizzle.
#define KT 64            // keys per tile
#define LDP 72           // Ps row pad (bf16 elems)
__global__ __launch_bounds__(256) void k_attn(const unsigned short* __restrict__ h,
                                              const unsigned short* __restrict__ vT,
                                              unsigned short* __restrict__ cat) {
    __shared__ alignas(16) unsigned short Ks[KT * 64];     // [key][d] swizzled
    __shared__ alignas(16) unsigned short Vs[HD * 64];     // [d][key] swizzled
    __shared__ unsigned short Ps[4 * 16 * LDP];            // per-wave [q][key]
    int t = threadIdx.x;
    int bx = blockIdx.x;               // Q tile (64 rows)
    int bh = blockIdx.y;               // 0..31
    int b = bh >> 4, hh = bh & 15;
    int lane = t & 63, w = t >> 6;
    int ln = lane & 15, quad = lane >> 4;
    int ln7 = ln & 7;
    const unsigned short* hb = h + (size_t)b * LL * D1;
    const unsigned short* vtb = vT + ((size_t)(b * NH + hh) * HD) * LL;

    bf16x8 qf[2];
    {
        const unsigned short* qbase = hb + (size_t)(bx * 64 + w * 16) * D1 + hh * HD;
        #pragma unroll
        for (int ks = 0; ks < 2; ks++)
            qf[ks] = *(const bf16x8*)(qbase + (size_t)ln * D1 + ks * 32 + quad * 8);
    }

    f32x4 O[4];
    #pragma unroll
    for (int vn = 0; vn < 4; vn++) O[vn] = {0.f, 0.f, 0.f, 0.f};
    float m_ = -1e30f, l_ = 0.f;

    unsigned short* Psw = Ps + w * 16 * LDP;

    int srow = t >> 3;                 // 0..31
    int scg  = (t & 7) ^ (srow & 7);   // global chunk for this LDS slot

    for (int kb = 0; kb < LL / KT; kb++) {
        __syncthreads();
        {   // stage K tile [64 key][64 d] and V^T tile [64 d][64 key]
            const unsigned short* kb0 = hb + (size_t)(kb * KT) * D1 + HID + hh * HD;
            gl_lds16(kb0 + (size_t)srow * D1 + scg * 8,        &Ks[t * 8]);
            gl_lds16(kb0 + (size_t)(srow + 32) * D1 + scg * 8, &Ks[2048 + t * 8]);
            const unsigned short* vb0 = vtb + kb * KT;
            gl_lds16(vb0 + (size_t)srow * LL + scg * 8,        &Vs[t * 8]);
            gl_lds16(vb0 + (size_t)(srow + 32) * LL + scg * 8, &Vs[2048 + t * 8]);
        }
        __syncthreads();

        // S^T = K @ Q^T : D[row=key=kt*16+quad*4+r][col=q=ln]
        f32x4 st[4];
        #pragma unroll
        for (int kt = 0; kt < 4; kt++) {
            st[kt] = {0.f, 0.f, 0.f, 0.f};
            #pragma unroll
            for (int ks = 0; ks < 2; ks++) {
                bf16x8 kf = *(const bf16x8*)(&Ks[(kt * 16 + ln) * 64 + (((ks * 4 + quad) ^ ln7) * 8)]);
                st[kt] = __builtin_amdgcn_mfma_f32_16x16x32_bf16(kf, qf[ks], st[kt], 0, 0, 0);
            }
        }

        // online softmax (exp2 domain)
        {
            float p[16];
            float mx = -1e30f;
            #pragma unroll
            for (int kt = 0; kt < 4; kt++)
                #pragma unroll
                for (int r = 0; r < 4; r++) {
                    float v = st[kt][r];
                    p[kt * 4 + r] = v;
                    mx = fmaxf(mx, v);
                }
            mx = fmaxf(mx, __shfl_xor(mx, 16));
            mx = fmaxf(mx, __shfl_xor(mx, 32));
            float mnew = fmaxf(m_, mx);
            float alpha = __builtin_amdgcn_exp2f(m_ - mnew);
            m_ = mnew;
            float sum = 0.f;
            #pragma unroll
            for (int i = 0; i < 16; i++) {
                float e = __builtin_amdgcn_exp2f(p[i] - mnew);
                p[i] = e;
                sum += e;
            }
            sum += __shfl_xor(sum, 16);
            sum += __shfl_xor(sum, 32);
            l_ = l_ * alpha + sum;
            #pragma unroll
            for (int vn = 0; vn < 4; vn++)
                #pragma unroll
                for (int r = 0; r < 4; r++) O[vn][r] *= alpha;
            #pragma unroll
            for (int kt = 0; kt < 4; kt++) {
                unsigned long long pk =
                    (unsigned long long)pkbf2(p[kt*4+0], p[kt*4+1])
                  | ((unsigned long long)pkbf2(p[kt*4+2], p[kt*4+3]) << 32);
                *(unsigned long long*)(&Psw[ln * LDP + kt * 16 + quad * 4]) = pk;
            }
        }

        // O^T += V^T @ P^T
        #pragma unroll
        for (int kt2 = 0; kt2 < 2; kt2++) {
            bf16x8 pb = *(const bf16x8*)(&Psw[ln * LDP + kt2 * 32 + quad * 8]);
            #pragma unroll
            for (int vn = 0; vn < 4; vn++) {
                bf16x8 vf = *(const bf16x8*)(&Vs[(vn * 16 + ln) * 64 + (((kt2 * 4 + quad) ^ ln7) * 8)]);
                O[vn] = __builtin_amdgcn_mfma_f32_16x16x32_bf16(vf, pb, O[vn], 0, 0, 0);
            }
        }
    }

    // epilogue: O^T[d][q] / l -> cat[token][hh*64+d]
    {
        float rl = 1.0f / l_;
        size_t row = (size_t)(b * LL + bx * 64 + w * 16 + ln);
        #pragma unroll
        for (int vn = 0; vn < 4; vn++) {
            #pragma unroll
            for (int r2 = 0; r2 < 4; r2 += 2) {
                unsigned int pk = pkbf2(O[vn][r2] * rl, O[vn][r2 + 1] * rl);
                *(unsigned int*)(&cat[row * DCAT + hh * HD + vn * 16 + quad * 4 + r2]) = pk;
            }
        }
    }
}

// ---------------- host launch ----------------
extern "C" void kernel_launch(void* const* d_in, const int* in_sizes, int n_in,
                              void* d_out, int out_size, void* d_ws, size_t ws_size,
                              hipStream_t stream) {
    const float* x       = (const float*)d_in[0];
    const float* vec     = (const float*)d_in[1];
    const float* pe      = (const float*)d_in[2];
    const float* w_mod   = (const float*)d_in[3];
    const float* b_mod   = (const float*)d_in[4];
    const float* w1      = (const float*)d_in[5];
    const float* b1      = (const float*)d_in[6];
    const float* w_mlp   = (const float*)d_in[7];
    const float* b_mlp   = (const float*)d_in[8];
    const float* w2      = (const float*)d_in[9];
    const float* b2      = (const float*)d_in[10];
    const float* q_scale = (const float*)d_in[11];
    const float* k_scale = (const float*)d_in[12];
    float* out = (float*)d_out;

    char* ws = (char*)d_ws;
    size_t off = 0;
    float* mod = (float*)(ws + off);                     off += 6144 * 4;
    unsigned short* xmod  = (unsigned short*)(ws + off); off += (size_t)TOK * HID * 2;
    unsigned short* h     = (unsigned short*)(ws + off); off += (size_t)TOK * D1 * 2;
    unsigned short* cat   = (unsigned short*)(ws + off); off += (size_t)TOK * DCAT * 2;
    unsigned short* w1T   = (unsigned short*)(ws + off); off += (size_t)D1 * HID * 2;
    unsigned short* wmlpT = (unsigned short*)(ws + off); off += (size_t)HID * MLP * 2;
    unsigned short* w2T   = (unsigned short*)(ws + off); off += (size_t)HID * DCAT * 2;
    unsigned short* vTr   = (unsigned short*)(ws + off); off += (size_t)BB * NH * HD * LL * 2;
    float* part = (float*)(ws + off);                    off += (size_t)2 * TOK * HID * 4;

    k_transpose_cvt<<<dim3(D1 / 32, HID / 32), dim3(32, 8), 0, stream>>>(w1, w1T, HID, D1);
    k_transpose_cvt<<<dim3(HID / 32, MLP / 32), dim3(32, 8), 0, stream>>>(w_mlp, wmlpT, MLP, HID);
    k_transpose_cvt<<<dim3(HID / 32, DCAT / 32), dim3(32, 8), 0, stream>>>(w2, w2T, DCAT, HID);

    k_mod<<<dim3(96, BB), 256, 0, stream>>>(vec, w_mod, b_mod, mod);
    k_lnmod<<<TOK, 256, 0, stream>>>(x, mod, xmod);

    // h = x_mod @ w1 + b1   (M=4096, N=7168, K=1024)
    k_gemm<0><<<dim3(TOK / 128, D1 / 128), 256, 0, stream>>>(
        xmod, HID, w1T, HID, b1, h, nullptr, D1, HID, nullptr, nullptr);

    k_vt<<<dim3(LL / 32, 2 * BB * NH), dim3(32, 8), 0, stream>>>(h, vTr);
    k_qkrope<<<TOK, 256, 0, stream>>>(h, pe, q_scale, k_scale);

    k_attn<<<dim3(LL / 64, BB * NH), 256, 0, stream>>>(h, vTr, cat);

    // mlp partials: h_mlp @ w_mlp   (M=4096, N=1024, K=4096, split-K=2)
    k_gemm<3><<<dim3(TOK / 128, HID / 128, 2), 256, 0, stream>>>(
        h + DQKV, D1, wmlpT, MLP, b_mlp, nullptr, part, HID, MLP, nullptr, nullptr);
    k_red1<<<TOK * HID / 1024, 256, 0, stream>>>(part, b_mlp, cat);

    // out partials: cat @ w2   (M=4096, N=1024, K=2048, split-K=2)
    k_gemm<3><<<dim3(TOK / 128, HID / 128, 2), 256, 0, stream>>>(
        cat, DCAT, w2T, DCAT, b2, nullptr, part, HID, DCAT, nullptr, nullptr);
    k_red2<<<TOK * HID / 1024, 256, 0, stream>>>(part, b2, x, mod, out);
}

// Round 8
// 429.046 us; speedup vs baseline: 1.0260x; 1.0260x over previous
//
#include <hip/hip_runtime.h>
#include <stdint.h>

// SingleStreamBlock on MI355X. fp32 in/out (per reference), bf16 MFMA compute.
// B=2 L=2048 HID=1024 NH=16 HD=64 MLP=4096.

#define HID  1024
#define NH   16
#define HD   64
#define MLP  4096
#define D1   7168   // 3*HID + MLP
#define DQKV 3072
#define DCAT 2048
#define BB   2
#define LL   2048
#define TOK  4096

typedef __attribute__((ext_vector_type(8))) short    bf16x8;
typedef __attribute__((ext_vector_type(4))) float    f32x4;
typedef __attribute__((ext_vector_type(4))) unsigned int u32x4;

__device__ __forceinline__ float b2f(unsigned short u) {
    unsigned int v = ((unsigned int)u) << 16;
    float f; __builtin_memcpy(&f, &v, 4); return f;
}
__device__ __forceinline__ unsigned short f2b(float f) {   // RNE
    unsigned int v; __builtin_memcpy(&v, &f, 4);
    unsigned int r = (v + 0x7FFFu + ((v >> 16) & 1u)) >> 16;
    return (unsigned short)r;
}
// cheap round-to-nearest pack of 2 floats -> 2 bf16 in a u32
__device__ __forceinline__ unsigned int pkbf2(float a, float b) {
    unsigned int ua, ub;
    __builtin_memcpy(&ua, &a, 4); __builtin_memcpy(&ub, &b, 4);
    return ((ua + 0x8000u) >> 16) | ((ub + 0x8000u) & 0xFFFF0000u);
}
// async global->LDS, 16 B per lane (dest is wave-uniform base + lane*16)
__device__ __forceinline__ void gl_lds16(const unsigned short* g, unsigned short* l) {
    __builtin_amdgcn_global_load_lds(
        (const __attribute__((address_space(1))) unsigned int*)(g),
        (__attribute__((address_space(3))) unsigned int*)(l), 16, 0, 0);
}

// ---------------- transpose+cast: fp32 (R x C) -> bf16 (C x R) ----------------
__global__ void k_transpose_cvt(const float* __restrict__ in,
                                unsigned short* __restrict__ out, int R, int C) {
    __shared__ float tile[32][33];
    int bx = blockIdx.x, by = blockIdx.y;
    int tx = threadIdx.x, ty = threadIdx.y;   // (32,8)
    #pragma unroll
    for (int i = 0; i < 4; i++) {
        int r = by * 32 + ty + i * 8;
        int c = bx * 32 + tx;
        tile[ty + i * 8][tx] = in[(size_t)r * C + c];
    }
    __syncthreads();
    #pragma unroll
    for (int i = 0; i < 4; i++) {
        int ro = bx * 32 + ty + i * 8;   // original col
        int co = by * 32 + tx;           // original row
        out[(size_t)ro * R + co] = f2b(tile[tx][ty + i * 8]);
    }
}

// ---------------- V transpose: h[:, 2048+h*64+d] -> vT[(b,h,d)][l] bf16 ----------------
__global__ void k_vt(const unsigned short* __restrict__ h,
                     unsigned short* __restrict__ vT) {
    __shared__ unsigned short tile[32][33];
    int l0 = blockIdx.x * 32;
    int d0 = (blockIdx.y & 1) * 32;
    int bh = blockIdx.y >> 1;
    int b = bh >> 4, hh = bh & 15;
    int tx = threadIdx.x, ty = threadIdx.y;   // (32,8)
    const unsigned short* src = h + ((size_t)(b * LL) + l0) * D1 + 2 * HID + hh * HD + d0;
    #pragma unroll
    for (int i = 0; i < 4; i++)
        tile[ty + i * 8][tx] = src[(size_t)(ty + i * 8) * D1 + tx];
    __syncthreads();
    unsigned short* dst = vT + ((size_t)(b * NH + hh) * HD + d0) * LL + l0;
    #pragma unroll
    for (int i = 0; i < 4; i++)
        dst[(size_t)(ty + i * 8) * LL + tx] = tile[tx][ty + i * 8];
}

// ---------------- mod = silu(vec) @ w_mod + b_mod (fp32) ----------------
__global__ void k_mod(const float* __restrict__ vec,
                      const float* __restrict__ w_mod,
                      const float* __restrict__ b_mod,
                      float* __restrict__ mod) {
    __shared__ float sv[HID];
    __shared__ float red[8][32];
    int b = blockIdx.y, t = threadIdx.x;
    for (int j = t; j < HID; j += 256) {
        float v = vec[b * HID + j];
        sv[j] = v / (1.0f + __expf(-v));
    }
    __syncthreads();
    int n0 = blockIdx.x * 32;
    int on = t & 31, ks = t >> 5;
    float acc = 0.f;
    const float* wp = w_mod + (size_t)(ks * 128) * 3072 + n0 + on;
    #pragma unroll 4
    for (int k = 0; k < 128; k++) acc += sv[ks * 128 + k] * wp[(size_t)k * 3072];
    red[ks][on] = acc;
    __syncthreads();
    if (t < 32) {
        float s = 0.f;
        #pragma unroll
        for (int i = 0; i < 8; i++) s += red[i][t];
        mod[b * 3072 + n0 + t] = s + b_mod[n0 + t];
    }
}

// ---------------- x_mod = (1+scale)*layernorm(x) + shift, bf16 out ----------------
__global__ void k_lnmod(const float* __restrict__ x,
                        const float* __restrict__ mod,
                        unsigned short* __restrict__ xmod) {
    int tok = blockIdx.x;
    int t = threadIdx.x;
    int b = tok >> 11;
    float4 v4 = *(const float4*)(x + (size_t)tok * HID + t * 4);
    float v0 = v4.x, v1 = v4.y, v2 = v4.z, v3 = v4.w;
    float s  = v0 + v1 + v2 + v3;
    float sq = v0*v0 + v1*v1 + v2*v2 + v3*v3;
    for (int off = 1; off < 64; off <<= 1) {
        s  += __shfl_xor(s,  off);
        sq += __shfl_xor(sq, off);
    }
    __shared__ float ls[4], lq[4];
    int w = t >> 6;
    if ((t & 63) == 0) { ls[w] = s; lq[w] = sq; }
    __syncthreads();
    s  = ls[0] + ls[1] + ls[2] + ls[3];
    sq = lq[0] + lq[1] + lq[2] + lq[3];
    float mean = s * (1.0f / HID);
    float var  = sq * (1.0f / HID) - mean * mean;
    float rstd = rsqrtf(var + 1e-6f);
    const float* mb = mod + b * 3072;
    float y[4] = {v0, v1, v2, v3};
    unsigned short r[4];
    #pragma unroll
    for (int j = 0; j < 4; j++) {
        int col = t * 4 + j;
        float nval = (y[j] - mean) * rstd;
        r[j] = f2b((1.0f + mb[1024 + col]) * nval + mb[col]);
    }
    unsigned int o0 = (unsigned int)r[0] | ((unsigned int)r[1] << 16);
    unsigned int o1 = (unsigned int)r[2] | ((unsigned int)r[3] << 16);
    *(uint2*)(xmod + (size_t)tok * HID + t * 4) = make_uint2(o0, o1);
}

// ---------------- MFMA GEMM (BK=64, global_load_lds, XOR-8 swizzle) ----------------
// C[M,N] = A[M,K](bf16) @ Bt[N,K](bf16)^T + bias(f32)
// Operand-swapped MFMA (D = C^T fragments): lane holds 4 consecutive N cols ->
// vectorized epilogue. Natural block mapping (bm = blockIdx.x fastest; panel
// swizzle regressed FETCH 73->138 MB in r7 -- do not reintroduce).
// EPI: 0 = store bf16; 1 = tanh -> bf16; 2 = out(f32) = x + gate*(acc+bias)
// EPI: 3 = split-K fp32 partial (no bias), gridDim.z splits K
template<int EPI>
__global__ __launch_bounds__(256) void k_gemm(
    const unsigned short* __restrict__ A, int lda,
    const unsigned short* __restrict__ Bt, int ldb,
    const float* __restrict__ bias,
    unsigned short* __restrict__ C, float* __restrict__ Cf, int ldc,
    int K,
    const float* __restrict__ xin,
    const float* __restrict__ mod) {
    __shared__ alignas(16) unsigned short As[128 * 64];
    __shared__ alignas(16) unsigned short Bs[128 * 64];
    int t = threadIdx.x;
    int bm = blockIdx.x, bn = blockIdx.y;
    int lane = t & 63, wave = t >> 6;
    int wm = (wave >> 1) * 64, wn = (wave & 1) * 64;
    int ln = lane & 15, quad = lane >> 4;
    int ln7 = ln & 7;

    f32x4 acc[4][4];
    #pragma unroll
    for (int i = 0; i < 4; i++)
        #pragma unroll
        for (int j = 0; j < 4; j++) acc[i][j] = {0.f, 0.f, 0.f, 0.f};

    int sr  = t >> 3;                    // staging row 0..31 (per 32-row group)
    int scg = (t & 7) ^ (sr & 7);        // global chunk fetched by this lane
    const unsigned short* Ab = A  + (size_t)(bm * 128) * lda;
    const unsigned short* Bb = Bt + (size_t)(bn * 128) * ldb;

    int ksplit = K / gridDim.z;
    int kbeg = blockIdx.z * ksplit, kend = kbeg + ksplit;

    for (int k0 = kbeg; k0 < kend; k0 += 64) {
        __syncthreads();
        #pragma unroll
        for (int c = 0; c < 4; c++) {
            gl_lds16(Ab + (size_t)(c * 32 + sr) * lda + k0 + scg * 8, &As[c * 2048 + t * 8]);
            gl_lds16(Bb + (size_t)(c * 32 + sr) * ldb + k0 + scg * 8, &Bs[c * 2048 + t * 8]);
        }
        __syncthreads();
        #pragma unroll
        for (int ks = 0; ks < 2; ks++) {
            int slot = ((ks * 4 + quad) ^ ln7) * 8;
            bf16x8 af[4], bfr[4];
            #pragma unroll
            for (int i = 0; i < 4; i++)
                af[i] = *(const bf16x8*)(&As[(wm + i * 16 + ln) * 64 + slot]);
            #pragma unroll
            for (int j = 0; j < 4; j++)
                bfr[j] = *(const bf16x8*)(&Bs[(wn + j * 16 + ln) * 64 + slot]);
            #pragma unroll
            for (int i = 0; i < 4; i++)
                #pragma unroll
                for (int j = 0; j < 4; j++)
                    // operand-swapped: D[row=n][col=m]
                    acc[i][j] = __builtin_amdgcn_mfma_f32_16x16x32_bf16(bfr[j], af[i], acc[i][j], 0, 0, 0);
        }
    }

    #pragma unroll
    for (int i = 0; i < 4; i++) {
        #pragma unroll
        for (int j = 0; j < 4; j++) {
            int trow = bm * 128 + wm + i * 16 + ln;        // M row (token)
            int ncol = bn * 128 + wn + j * 16 + quad * 4;  // N col base, 4 consecutive
            f32x4 a = acc[i][j];
            if (EPI == 3) {
                float4 o = make_float4(a[0], a[1], a[2], a[3]);
                *(float4*)(&Cf[((size_t)blockIdx.z * TOK + trow) * ldc + ncol]) = o;
            } else {
                float4 bv = *(const float4*)(bias + ncol);
                float v0 = a[0] + bv.x, v1 = a[1] + bv.y, v2 = a[2] + bv.z, v3 = a[3] + bv.w;
                if (EPI == 1) { v0 = tanhf(v0); v1 = tanhf(v1); v2 = tanhf(v2); v3 = tanhf(v3); }
                if (EPI == 0 || EPI == 1) {
                    *(uint2*)(&C[(size_t)trow * ldc + ncol]) =
                        make_uint2(pkbf2(v0, v1), pkbf2(v2, v3));
                } else {
                    int b = trow >> 11;
                    float4 gv = *(const float4*)(mod + b * 3072 + 2048 + ncol);
                    float4 xv = *(const float4*)(xin + (size_t)trow * HID + ncol);
                    float4 o = make_float4(xv.x + gv.x * v0, xv.y + gv.y * v1,
                                           xv.z + gv.z * v2, xv.w + gv.w * v3);
                    *(float4*)(&Cf[(size_t)trow * ldc + ncol]) = o;
                }
            }
        }
    }
}

// ---------------- split-K reduce 1: cat[:,1024:] = tanh(p0+p1+bias) ----------------
__global__ __launch_bounds__(256) void k_red1(const float* __restrict__ part,
                                              const float* __restrict__ bias,
                                              unsigned short* __restrict__ cat) {
    int idx = blockIdx.x * 256 + threadIdx.x;
    int row = idx >> 8;
    int c4  = (idx & 255) * 4;
    float4 p0 = *(const float4*)(part + (size_t)row * HID + c4);
    float4 p1 = *(const float4*)(part + ((size_t)TOK + row) * HID + c4);
    float4 bv = *(const float4*)(bias + c4);
    float a0 = tanhf(p0.x + p1.x + bv.x);
    float a1 = tanhf(p0.y + p1.y + bv.y);
    float a2 = tanhf(p0.z + p1.z + bv.z);
    float a3 = tanhf(p0.w + p1.w + bv.w);
    *(uint2*)(&cat[(size_t)row * DCAT + HID + c4]) =
        make_uint2(pkbf2(a0, a1), pkbf2(a2, a3));
}

// ---------------- split-K reduce 2: out = x + gate*(p0+p1+bias) (fp32) ----------------
__global__ __launch_bounds__(256) void k_red2(const float* __restrict__ part,
                                              const float* __restrict__ bias,
                                              const float* __restrict__ x,
                                              const float* __restrict__ mod,
                                              float* __restrict__ out) {
    int idx = blockIdx.x * 256 + threadIdx.x;
    int row = idx >> 8;
    int c4  = (idx & 255) * 4;
    int b = row >> 11;
    float4 p0 = *(const float4*)(part + (size_t)row * HID + c4);
    float4 p1 = *(const float4*)(part + ((size_t)TOK + row) * HID + c4);
    float4 bv = *(const float4*)(bias + c4);
    float4 gv = *(const float4*)(mod + b * 3072 + 2048 + c4);
    float4 xv = *(const float4*)(x + (size_t)row * HID + c4);
    float4 o;
    o.x = xv.x + gv.x * (p0.x + p1.x + bv.x);
    o.y = xv.y + gv.y * (p0.y + p1.y + bv.y);
    o.z = xv.z + gv.z * (p0.z + p1.z + bv.z);
    o.w = xv.w + gv.w * (p0.w + p1.w + bv.w);
    *(float4*)(out + (size_t)row * HID + c4) = o;
}

// ---------------- per-head RMSNorm + RoPE on q,k (in place in h, bf16) ----------------
// q additionally pre-scaled by 0.125*log2(e) so attention softmax runs in exp2 domain.
__global__ void k_qkrope(unsigned short* __restrict__ h,
                         const float* __restrict__ pe,
                         const float* __restrict__ q_scale,
                         const float* __restrict__ k_scale) {
    int tok = blockIdx.x;
    int l = tok & (LL - 1);
    int t = threadIdx.x;
    int lane = t & 63, wave = t >> 6;
    int hh = wave * 4 + (lane >> 4);      // head 0..15
    int d0 = (lane & 15) * 4;             // 4 dims = 2 rope pairs
    unsigned short* row = h + (size_t)tok * D1;
    int i0 = d0 >> 1;
    const float* peb = pe + ((size_t)l * 32 + i0) * 4;
    float4 e0 = *(const float4*)(peb);
    float4 e1 = *(const float4*)(peb + 4);
    #pragma unroll
    for (int qk = 0; qk < 2; qk++) {
        unsigned short* p = row + qk * HID + hh * HD + d0;
        const float* sc = (qk == 0 ? q_scale : k_scale) + d0;
        uint2 qv = *(const uint2*)p;
        float v0 = b2f((unsigned short)(qv.x & 0xFFFF)), v1 = b2f((unsigned short)(qv.x >> 16));
        float v2 = b2f((unsigned short)(qv.y & 0xFFFF)), v3 = b2f((unsigned short)(qv.y >> 16));
        float ssq = v0*v0 + v1*v1 + v2*v2 + v3*v3;
        ssq += __shfl_xor(ssq, 1, 16);
        ssq += __shfl_xor(ssq, 2, 16);
        ssq += __shfl_xor(ssq, 4, 16);
        ssq += __shfl_xor(ssq, 8, 16);
        float rr = rsqrtf(ssq * (1.0f / HD) + 1e-6f);
        if (qk == 0) rr *= 0.18033688011112042f;   // 0.125 * log2(e)
        v0 *= rr * sc[0];
        v1 *= rr * sc[1];
        v2 *= rr * sc[2];
        v3 *= rr * sc[3];
        float o0 = e0.x*v0 + e0.y*v1;
        float o1 = e0.z*v0 + e0.w*v1;
        float o2 = e1.x*v2 + e1.y*v3;
        float o3 = e1.z*v2 + e1.w*v3;
        *(uint2*)p = make_uint2(pkbf2(o0, o1), pkbf2(o2, o3));
    }
}

// ---------------- MFMA flash attention (exp2 domain, 64 Q-rows/block) ----------------
// K and V^T staged with global_load_lds into unpadded [64][64] + XOR-8 swizzle.
#define KT 64            // keys per tile
#define LDP 72           // Ps row pad (bf16 elems)
__global__ __launch_bounds__(256) void k_attn(const unsigned short* __restrict__ h,
                                              const unsigned short* __restrict__ vT,
                                              unsigned short* __restrict__ cat) {
    __shared__ alignas(16) unsigned short Ks[KT * 64];     // [key][d] swizzled
    __shared__ alignas(16) unsigned short Vs[HD * 64];     // [d][key] swizzled
    __shared__ unsigned short Ps[4 * 16 * LDP];            // per-wave [q][key]
    int t = threadIdx.x;
    int bx = blockIdx.x;               // Q tile (64 rows)
    int bh = blockIdx.y;               // 0..31
    int b = bh >> 4, hh = bh & 15;
    int lane = t & 63, w = t >> 6;
    int ln = lane & 15, quad = lane >> 4;
    int ln7 = ln & 7;
    const unsigned short* hb = h + (size_t)b * LL * D1;
    const unsigned short* vtb = vT + ((size_t)(b * NH + hh) * HD) * LL;

    bf16x8 qf[2];
    {
        const unsigned short* qbase = hb + (size_t)(bx * 64 + w * 16) * D1 + hh * HD;
        #pragma unroll
        for (int ks = 0; ks < 2; ks++)
            qf[ks] = *(const bf16x8*)(qbase + (size_t)ln * D1 + ks * 32 + quad * 8);
    }

    f32x4 O[4];
    #pragma unroll
    for (int vn = 0; vn < 4; vn++) O[vn] = {0.f, 0.f, 0.f, 0.f};
    float m_ = -1e30f, l_ = 0.f;

    unsigned short* Psw = Ps + w * 16 * LDP;

    int srow = t >> 3;                 // 0..31
    int scg  = (t & 7) ^ (srow & 7);   // global chunk for this LDS slot

    for (int kb = 0; kb < LL / KT; kb++) {
        __syncthreads();
        {   // stage K tile [64 key][64 d] and V^T tile [64 d][64 key]
            const unsigned short* kb0 = hb + (size_t)(kb * KT) * D1 + HID + hh * HD;
            gl_lds16(kb0 + (size_t)srow * D1 + scg * 8,        &Ks[t * 8]);
            gl_lds16(kb0 + (size_t)(srow + 32) * D1 + scg * 8, &Ks[2048 + t * 8]);
            const unsigned short* vb0 = vtb + kb * KT;
            gl_lds16(vb0 + (size_t)srow * LL + scg * 8,        &Vs[t * 8]);
            gl_lds16(vb0 + (size_t)(srow + 32) * LL + scg * 8, &Vs[2048 + t * 8]);
        }
        __syncthreads();

        // S^T = K @ Q^T : D[row=key=kt*16+quad*4+r][col=q=ln]
        f32x4 st[4];
        #pragma unroll
        for (int kt = 0; kt < 4; kt++) {
            st[kt] = {0.f, 0.f, 0.f, 0.f};
            #pragma unroll
            for (int ks = 0; ks < 2; ks++) {
                bf16x8 kf = *(const bf16x8*)(&Ks[(kt * 16 + ln) * 64 + (((ks * 4 + quad) ^ ln7) * 8)]);
                st[kt] = __builtin_amdgcn_mfma_f32_16x16x32_bf16(kf, qf[ks], st[kt], 0, 0, 0);
            }
        }

        // online softmax (exp2 domain)
        {
            float p[16];
            float mx = -1e30f;
            #pragma unroll
            for (int kt = 0; kt < 4; kt++)
                #pragma unroll
                for (int r = 0; r < 4; r++) {
                    float v = st[kt][r];
                    p[kt * 4 + r] = v;
                    mx = fmaxf(mx, v);
                }
            mx = fmaxf(mx, __shfl_xor(mx, 16));
            mx = fmaxf(mx, __shfl_xor(mx, 32));
            float mnew = fmaxf(m_, mx);
            float alpha = __builtin_amdgcn_exp2f(m_ - mnew);
            m_ = mnew;
            float sum = 0.f;
            #pragma unroll
            for (int i = 0; i < 16; i++) {
                float e = __builtin_amdgcn_exp2f(p[i] - mnew);
                p[i] = e;
                sum += e;
            }
            sum += __shfl_xor(sum, 16);
            sum += __shfl_xor(sum, 32);
            l_ = l_ * alpha + sum;
            #pragma unroll
            for (int vn = 0; vn < 4; vn++)
                #pragma unroll
                for (int r = 0; r < 4; r++) O[vn][r] *= alpha;
            #pragma unroll
            for (int kt = 0; kt < 4; kt++) {
                unsigned long long pk =
                    (unsigned long long)pkbf2(p[kt*4+0], p[kt*4+1])
                  | ((unsigned long long)pkbf2(p[kt*4+2], p[kt*4+3]) << 32);
                *(unsigned long long*)(&Psw[ln * LDP + kt * 16 + quad * 4]) = pk;
            }
        }

        // O^T += V^T @ P^T
        #pragma unroll
        for (int kt2 = 0; kt2 < 2; kt2++) {
            bf16x8 pb = *(const bf16x8*)(&Psw[ln * LDP + kt2 * 32 + quad * 8]);
            #pragma unroll
            for (int vn = 0; vn < 4; vn++) {
                bf16x8 vf = *(const bf16x8*)(&Vs[(vn * 16 + ln) * 64 + (((kt2 * 4 + quad) ^ ln7) * 8)]);
                O[vn] = __builtin_amdgcn_mfma_f32_16x16x32_bf16(vf, pb, O[vn], 0, 0, 0);
            }
        }
    }

    // epilogue: O^T[d][q] / l -> cat[token][hh*64+d]
    {
        float rl = 1.0f / l_;
        size_t row = (size_t)(b * LL + bx * 64 + w * 16 + ln);
        #pragma unroll
        for (int vn = 0; vn < 4; vn++) {
            #pragma unroll
            for (int r2 = 0; r2 < 4; r2 += 2) {
                unsigned int pk = pkbf2(O[vn][r2] * rl, O[vn][r2 + 1] * rl);
                *(unsigned int*)(&cat[row * DCAT + hh * HD + vn * 16 + quad * 4 + r2]) = pk;
            }
        }
    }
}

// ---------------- host launch ----------------
extern "C" void kernel_launch(void* const* d_in, const int* in_sizes, int n_in,
                              void* d_out, int out_size, void* d_ws, size_t ws_size,
                              hipStream_t stream) {
    const float* x       = (const float*)d_in[0];
    const float* vec     = (const float*)d_in[1];
    const float* pe      = (const float*)d_in[2];
    const float* w_mod   = (const float*)d_in[3];
    const float* b_mod   = (const float*)d_in[4];
    const float* w1      = (const float*)d_in[5];
    const float* b1      = (const float*)d_in[6];
    const float* w_mlp   = (const float*)d_in[7];
    const float* b_mlp   = (const float*)d_in[8];
    const float* w2      = (const float*)d_in[9];
    const float* b2      = (const float*)d_in[10];
    const float* q_scale = (const float*)d_in[11];
    const float* k_scale = (const float*)d_in[12];
    float* out = (float*)d_out;

    char* ws = (char*)d_ws;
    size_t off = 0;
    float* mod = (float*)(ws + off);                     off += 6144 * 4;
    unsigned short* xmod  = (unsigned short*)(ws + off); off += (size_t)TOK * HID * 2;
    unsigned short* h     = (unsigned short*)(ws + off); off += (size_t)TOK * D1 * 2;
    unsigned short* cat   = (unsigned short*)(ws + off); off += (size_t)TOK * DCAT * 2;
    unsigned short* w1T   = (unsigned short*)(ws + off); off += (size_t)D1 * HID * 2;
    unsigned short* wmlpT = (unsigned short*)(ws + off); off += (size_t)HID * MLP * 2;
    unsigned short* w2T   = (unsigned short*)(ws + off); off += (size_t)HID * DCAT * 2;
    unsigned short* vTr   = (unsigned short*)(ws + off); off += (size_t)BB * NH * HD * LL * 2;
    float* part = (float*)(ws + off);                    off += (size_t)2 * TOK * HID * 4;

    k_transpose_cvt<<<dim3(D1 / 32, HID / 32), dim3(32, 8), 0, stream>>>(w1, w1T, HID, D1);
    k_transpose_cvt<<<dim3(HID / 32, MLP / 32), dim3(32, 8), 0, stream>>>(w_mlp, wmlpT, MLP, HID);
    k_transpose_cvt<<<dim3(HID / 32, DCAT / 32), dim3(32, 8), 0, stream>>>(w2, w2T, DCAT, HID);

    k_mod<<<dim3(96, BB), 256, 0, stream>>>(vec, w_mod, b_mod, mod);
    k_lnmod<<<TOK, 256, 0, stream>>>(x, mod, xmod);

    // h = x_mod @ w1 + b1   (M=4096, N=7168, K=1024)
    k_gemm<0><<<dim3(TOK / 128, D1 / 128), 256, 0, stream>>>(
        xmod, HID, w1T, HID, b1, h, nullptr, D1, HID, nullptr, nullptr);

    k_vt<<<dim3(LL / 32, 2 * BB * NH), dim3(32, 8), 0, stream>>>(h, vTr);
    k_qkrope<<<TOK, 256, 0, stream>>>(h, pe, q_scale, k_scale);

    k_attn<<<dim3(LL / 64, BB * NH), 256, 0, stream>>>(h, vTr, cat);

    // mlp partials: h_mlp @ w_mlp   (M=4096, N=1024, K=4096, split-K=2)
    k_gemm<3><<<dim3(TOK / 128, HID / 128, 2), 256, 0, stream>>>(
        h + DQKV, D1, wmlpT, MLP, b_mlp, nullptr, part, HID, MLP, nullptr, nullptr);
    k_red1<<<TOK * HID / 1024, 256, 0, stream>>>(part, b_mlp, cat);

    // out partials: cat @ w2   (M=4096, N=1024, K=2048, split-K=2)
    k_gemm<3><<<dim3(TOK / 128, HID / 128, 2), 256, 0, stream>>>(
        cat, DCAT, w2T, DCAT, b2, nullptr, part, HID, DCAT, nullptr, nullptr);
    k_red2<<<TOK * HID / 1024, 256, 0, stream>>>(part, b2, x, mod, out);
}

// Round 9
// 426.860 us; speedup vs baseline: 1.0312x; 1.0051x over previous
//
#include <hip/hip_runtime.h>
#include <stdint.h>

// SingleStreamBlock on MI355X. fp32 in/out (per reference), bf16 MFMA compute.
// B=2 L=2048 HID=1024 NH=16 HD=64 MLP=4096.

#define HID  1024
#define NH   16
#define HD   64
#define MLP  4096
#define D1   7168   // 3*HID + MLP
#define DQKV 3072
#define DCAT 2048
#define BB   2
#define LL   2048
#define TOK  4096

typedef __attribute__((ext_vector_type(8))) short    bf16x8;
typedef __attribute__((ext_vector_type(4))) float    f32x4;
typedef __attribute__((ext_vector_type(4))) unsigned int u32x4;

__device__ __forceinline__ float b2f(unsigned short u) {
    unsigned int v = ((unsigned int)u) << 16;
    float f; __builtin_memcpy(&f, &v, 4); return f;
}
__device__ __forceinline__ unsigned short f2b(float f) {   // RNE
    unsigned int v; __builtin_memcpy(&v, &f, 4);
    unsigned int r = (v + 0x7FFFu + ((v >> 16) & 1u)) >> 16;
    return (unsigned short)r;
}
// cheap round-to-nearest pack of 2 floats -> 2 bf16 in a u32
__device__ __forceinline__ unsigned int pkbf2(float a, float b) {
    unsigned int ua, ub;
    __builtin_memcpy(&ua, &a, 4); __builtin_memcpy(&ub, &b, 4);
    return ((ua + 0x8000u) >> 16) | ((ub + 0x8000u) & 0xFFFF0000u);
}
// async global->LDS, 16 B per lane (dest is wave-uniform base + lane*16)
__device__ __forceinline__ void gl_lds16(const unsigned short* g, unsigned short* l) {
    __builtin_amdgcn_global_load_lds(
        (const __attribute__((address_space(1))) unsigned int*)(g),
        (__attribute__((address_space(3))) unsigned int*)(l), 16, 0, 0);
}

// ---------------- transpose+cast: fp32 (R x C) -> bf16 (C x R) ----------------
__global__ void k_transpose_cvt(const float* __restrict__ in,
                                unsigned short* __restrict__ out, int R, int C) {
    __shared__ float tile[32][33];
    int bx = blockIdx.x, by = blockIdx.y;
    int tx = threadIdx.x, ty = threadIdx.y;   // (32,8)
    #pragma unroll
    for (int i = 0; i < 4; i++) {
        int r = by * 32 + ty + i * 8;
        int c = bx * 32 + tx;
        tile[ty + i * 8][tx] = in[(size_t)r * C + c];
    }
    __syncthreads();
    #pragma unroll
    for (int i = 0; i < 4; i++) {
        int ro = bx * 32 + ty + i * 8;   // original col
        int co = by * 32 + tx;           // original row
        out[(size_t)ro * R + co] = f2b(tile[tx][ty + i * 8]);
    }
}

// ---------------- mod = silu(vec) @ w_mod + b_mod (fp32) ----------------
__global__ void k_mod(const float* __restrict__ vec,
                      const float* __restrict__ w_mod,
                      const float* __restrict__ b_mod,
                      float* __restrict__ mod) {
    __shared__ float sv[HID];
    __shared__ float red[8][32];
    int b = blockIdx.y, t = threadIdx.x;
    for (int j = t; j < HID; j += 256) {
        float v = vec[b * HID + j];
        sv[j] = v / (1.0f + __expf(-v));
    }
    __syncthreads();
    int n0 = blockIdx.x * 32;
    int on = t & 31, ks = t >> 5;
    float acc = 0.f;
    const float* wp = w_mod + (size_t)(ks * 128) * 3072 + n0 + on;
    #pragma unroll 4
    for (int k = 0; k < 128; k++) acc += sv[ks * 128 + k] * wp[(size_t)k * 3072];
    red[ks][on] = acc;
    __syncthreads();
    if (t < 32) {
        float s = 0.f;
        #pragma unroll
        for (int i = 0; i < 8; i++) s += red[i][t];
        mod[b * 3072 + n0 + t] = s + b_mod[n0 + t];
    }
}

// ---------------- x_mod = (1+scale)*layernorm(x) + shift, bf16 out ----------------
__global__ void k_lnmod(const float* __restrict__ x,
                        const float* __restrict__ mod,
                        unsigned short* __restrict__ xmod) {
    int tok = blockIdx.x;
    int t = threadIdx.x;
    int b = tok >> 11;
    float4 v4 = *(const float4*)(x + (size_t)tok * HID + t * 4);
    float v0 = v4.x, v1 = v4.y, v2 = v4.z, v3 = v4.w;
    float s  = v0 + v1 + v2 + v3;
    float sq = v0*v0 + v1*v1 + v2*v2 + v3*v3;
    for (int off = 1; off < 64; off <<= 1) {
        s  += __shfl_xor(s,  off);
        sq += __shfl_xor(sq, off);
    }
    __shared__ float ls[4], lq[4];
    int w = t >> 6;
    if ((t & 63) == 0) { ls[w] = s; lq[w] = sq; }
    __syncthreads();
    s  = ls[0] + ls[1] + ls[2] + ls[3];
    sq = lq[0] + lq[1] + lq[2] + lq[3];
    float mean = s * (1.0f / HID);
    float var  = sq * (1.0f / HID) - mean * mean;
    float rstd = rsqrtf(var + 1e-6f);
    const float* mb = mod + b * 3072;
    float y[4] = {v0, v1, v2, v3};
    unsigned short r[4];
    #pragma unroll
    for (int j = 0; j < 4; j++) {
        int col = t * 4 + j;
        float nval = (y[j] - mean) * rstd;
        r[j] = f2b((1.0f + mb[1024 + col]) * nval + mb[col]);
    }
    unsigned int o0 = (unsigned int)r[0] | ((unsigned int)r[1] << 16);
    unsigned int o1 = (unsigned int)r[2] | ((unsigned int)r[3] << 16);
    *(uint2*)(xmod + (size_t)tok * HID + t * 4) = make_uint2(o0, o1);
}

// ---------------- MFMA GEMM (BK=64, global_load_lds, XOR-8 swizzle) ----------------
// C[M,N] = A[M,K](bf16) @ Bt[N,K](bf16)^T + bias(f32)
// Operand-swapped MFMA: acc[i][j][r] = C[trow = wm+i*16+ln][ncol = wn+j*16+quad*4+r]
// -> one head's 64 cols live in one wave (4 quads) for each row: fused RMS+RoPE.
// EPI: 1 = tanh -> bf16; 2 = out(f32) = x + gate*(acc+bias)
// EPI: 3 = split-K fp32 partial (no bias), gridDim.z splits K
// EPI: 4 = GEMM0 fused epilogue: q/k -> RMSNorm+RoPE -> C(h); v -> vT transposed; mlp -> C(h)
template<int EPI>
__global__ __launch_bounds__(256) void k_gemm(
    const unsigned short* __restrict__ A, int lda,
    const unsigned short* __restrict__ Bt, int ldb,
    const float* __restrict__ bias,
    unsigned short* __restrict__ C, float* __restrict__ Cf, int ldc,
    int K,
    const float* __restrict__ xin,
    const float* __restrict__ mod,
    unsigned short* __restrict__ vT,
    const float* __restrict__ pe,
    const float* __restrict__ q_scale,
    const float* __restrict__ k_scale) {
    __shared__ alignas(16) unsigned short As[128 * 64];
    __shared__ alignas(16) unsigned short Bs[128 * 64];
    int t = threadIdx.x;
    int bm = blockIdx.x, bn = blockIdx.y;   // natural mapping (r7 swizzle regressed)
    int lane = t & 63, wave = t >> 6;
    int wm = (wave >> 1) * 64, wn = (wave & 1) * 64;
    int ln = lane & 15, quad = lane >> 4;
    int ln7 = ln & 7;

    f32x4 acc[4][4];
    #pragma unroll
    for (int i = 0; i < 4; i++)
        #pragma unroll
        for (int j = 0; j < 4; j++) acc[i][j] = {0.f, 0.f, 0.f, 0.f};

    int sr  = t >> 3;                    // staging row 0..31 (per 32-row group)
    int scg = (t & 7) ^ (sr & 7);        // global chunk fetched by this lane
    const unsigned short* Ab = A  + (size_t)(bm * 128) * lda;
    const unsigned short* Bb = Bt + (size_t)(bn * 128) * ldb;

    int ksplit = K / gridDim.z;
    int kbeg = blockIdx.z * ksplit, kend = kbeg + ksplit;

    for (int k0 = kbeg; k0 < kend; k0 += 64) {
        __syncthreads();
        #pragma unroll
        for (int c = 0; c < 4; c++) {
            gl_lds16(Ab + (size_t)(c * 32 + sr) * lda + k0 + scg * 8, &As[c * 2048 + t * 8]);
            gl_lds16(Bb + (size_t)(c * 32 + sr) * ldb + k0 + scg * 8, &Bs[c * 2048 + t * 8]);
        }
        __syncthreads();
        #pragma unroll
        for (int ks = 0; ks < 2; ks++) {
            int slot = ((ks * 4 + quad) ^ ln7) * 8;
            bf16x8 af[4], bfr[4];
            #pragma unroll
            for (int i = 0; i < 4; i++)
                af[i] = *(const bf16x8*)(&As[(wm + i * 16 + ln) * 64 + slot]);
            #pragma unroll
            for (int j = 0; j < 4; j++)
                bfr[j] = *(const bf16x8*)(&Bs[(wn + j * 16 + ln) * 64 + slot]);
            #pragma unroll
            for (int i = 0; i < 4; i++)
                #pragma unroll
                for (int j = 0; j < 4; j++)
                    acc[i][j] = __builtin_amdgcn_mfma_f32_16x16x32_bf16(bfr[j], af[i], acc[i][j], 0, 0, 0);
        }
    }

    if (EPI == 4) {
        // add bias
        #pragma unroll
        for (int j = 0; j < 4; j++) {
            int ncol = bn * 128 + wn + j * 16 + quad * 4;
            float4 bv = *(const float4*)(bias + ncol);
            #pragma unroll
            for (int i = 0; i < 4; i++) {
                acc[i][j][0] += bv.x; acc[i][j][1] += bv.y;
                acc[i][j][2] += bv.z; acc[i][j][3] += bv.w;
            }
        }
        int region = bn >> 3;            // 0=q, 1=k, 2=v, >=3 mlp
        if (region <= 1) {
            const float* scp = (region == 0) ? q_scale : k_scale;
            float4 sc4[4];
            #pragma unroll
            for (int j = 0; j < 4; j++)
                sc4[j] = *(const float4*)(scp + j * 16 + quad * 4);
            #pragma unroll
            for (int i = 0; i < 4; i++) {
                int trow = bm * 128 + wm + i * 16 + ln;
                int l = trow & (LL - 1);
                float ssq = 0.f;
                #pragma unroll
                for (int j = 0; j < 4; j++)
                    #pragma unroll
                    for (int r = 0; r < 4; r++) ssq += acc[i][j][r] * acc[i][j][r];
                ssq += __shfl_xor(ssq, 16);
                ssq += __shfl_xor(ssq, 32);
                float rr = rsqrtf(ssq * (1.0f / HD) + 1e-6f);
                if (region == 0) rr *= 0.18033688011112042f;   // 0.125 * log2(e)
                #pragma unroll
                for (int j = 0; j < 4; j++) {
                    float v0 = acc[i][j][0] * rr * sc4[j].x;
                    float v1 = acc[i][j][1] * rr * sc4[j].y;
                    float v2 = acc[i][j][2] * rr * sc4[j].z;
                    float v3 = acc[i][j][3] * rr * sc4[j].w;
                    const float* peb = pe + ((size_t)l * 32 + j * 8 + quad * 2) * 4;
                    float4 e0 = *(const float4*)(peb);
                    float4 e1 = *(const float4*)(peb + 4);
                    float o0 = e0.x * v0 + e0.y * v1;
                    float o1 = e0.z * v0 + e0.w * v1;
                    float o2 = e1.x * v2 + e1.y * v3;
                    float o3 = e1.z * v2 + e1.w * v3;
                    int ncol = bn * 128 + wn + j * 16 + quad * 4;
                    *(uint2*)(&C[(size_t)trow * ldc + ncol]) =
                        make_uint2(pkbf2(o0, o1), pkbf2(o2, o3));
                }
            }
        } else if (region == 2) {
            int hh = (bn * 128 + wn - 2048) >> 6;
            #pragma unroll
            for (int i = 0; i < 4; i++) {
                int trow = bm * 128 + wm + i * 16 + ln;
                int b = trow >> 11, l = trow & (LL - 1);
                unsigned short* dstb = vT + ((size_t)(b * NH + hh) * HD) * LL + l;
                #pragma unroll
                for (int j = 0; j < 4; j++) {
                    int d0 = j * 16 + quad * 4;
                    #pragma unroll
                    for (int r = 0; r < 4; r++)
                        dstb[(size_t)(d0 + r) * LL] = f2b(acc[i][j][r]);
                }
            }
        } else {
            #pragma unroll
            for (int i = 0; i < 4; i++) {
                int trow = bm * 128 + wm + i * 16 + ln;
                #pragma unroll
                for (int j = 0; j < 4; j++) {
                    int ncol = bn * 128 + wn + j * 16 + quad * 4;
                    *(uint2*)(&C[(size_t)trow * ldc + ncol]) =
                        make_uint2(pkbf2(acc[i][j][0], acc[i][j][1]),
                                   pkbf2(acc[i][j][2], acc[i][j][3]));
                }
            }
        }
        return;
    }

    #pragma unroll
    for (int i = 0; i < 4; i++) {
        #pragma unroll
        for (int j = 0; j < 4; j++) {
            int trow = bm * 128 + wm + i * 16 + ln;        // M row (token)
            int ncol = bn * 128 + wn + j * 16 + quad * 4;  // N col base, 4 consecutive
            f32x4 a = acc[i][j];
            if (EPI == 3) {
                float4 o = make_float4(a[0], a[1], a[2], a[3]);
                *(float4*)(&Cf[((size_t)blockIdx.z * TOK + trow) * ldc + ncol]) = o;
            } else {
                float4 bv = *(const float4*)(bias + ncol);
                float v0 = a[0] + bv.x, v1 = a[1] + bv.y, v2 = a[2] + bv.z, v3 = a[3] + bv.w;
                if (EPI == 1) { v0 = tanhf(v0); v1 = tanhf(v1); v2 = tanhf(v2); v3 = tanhf(v3); }
                if (EPI == 1) {
                    *(uint2*)(&C[(size_t)trow * ldc + ncol]) =
                        make_uint2(pkbf2(v0, v1), pkbf2(v2, v3));
                } else {
                    int b = trow >> 11;
                    float4 gv = *(const float4*)(mod + b * 3072 + 2048 + ncol);
                    float4 xv = *(const float4*)(xin + (size_t)trow * HID + ncol);
                    float4 o = make_float4(xv.x + gv.x * v0, xv.y + gv.y * v1,
                                           xv.z + gv.z * v2, xv.w + gv.w * v3);
                    *(float4*)(&Cf[(size_t)trow * ldc + ncol]) = o;
                }
            }
        }
    }
}

// ---------------- split-K reduce 1: cat[:,1024:] = tanh(p0+p1+bias) ----------------
__global__ __launch_bounds__(256) void k_red1(const float* __restrict__ part,
                                              const float* __restrict__ bias,
                                              unsigned short* __restrict__ cat) {
    int idx = blockIdx.x * 256 + threadIdx.x;
    int row = idx >> 8;
    int c4  = (idx & 255) * 4;
    float4 p0 = *(const float4*)(part + (size_t)row * HID + c4);
    float4 p1 = *(const float4*)(part + ((size_t)TOK + row) * HID + c4);
    float4 bv = *(const float4*)(bias + c4);
    float a0 = tanhf(p0.x + p1.x + bv.x);
    float a1 = tanhf(p0.y + p1.y + bv.y);
    float a2 = tanhf(p0.z + p1.z + bv.z);
    float a3 = tanhf(p0.w + p1.w + bv.w);
    *(uint2*)(&cat[(size_t)row * DCAT + HID + c4]) =
        make_uint2(pkbf2(a0, a1), pkbf2(a2, a3));
}

// ---------------- split-K reduce 2: out = x + gate*(p0+p1+bias) (fp32) ----------------
__global__ __launch_bounds__(256) void k_red2(const float* __restrict__ part,
                                              const float* __restrict__ bias,
                                              const float* __restrict__ x,
                                              const float* __restrict__ mod,
                                              float* __restrict__ out) {
    int idx = blockIdx.x * 256 + threadIdx.x;
    int row = idx >> 8;
    int c4  = (idx & 255) * 4;
    int b = row >> 11;
    float4 p0 = *(const float4*)(part + (size_t)row * HID + c4);
    float4 p1 = *(const float4*)(part + ((size_t)TOK + row) * HID + c4);
    float4 bv = *(const float4*)(bias + c4);
    float4 gv = *(const float4*)(mod + b * 3072 + 2048 + c4);
    float4 xv = *(const float4*)(x + (size_t)row * HID + c4);
    float4 o;
    o.x = xv.x + gv.x * (p0.x + p1.x + bv.x);
    o.y = xv.y + gv.y * (p0.y + p1.y + bv.y);
    o.z = xv.z + gv.z * (p0.z + p1.z + bv.z);
    o.w = xv.w + gv.w * (p0.w + p1.w + bv.w);
    *(float4*)(out + (size_t)row * HID + c4) = o;
}

// ---------------- MFMA flash attention (exp2 domain, 64 Q-rows/block) ----------------
// K and V^T staged with global_load_lds into unpadded [64][64] + XOR-8 swizzle.
#define KT 64            // keys per tile
#define LDP 72           // Ps row pad (bf16 elems)
__global__ __launch_bounds__(256) void k_attn(const unsigned short* __restrict__ h,
                                              const unsigned short* __restrict__ vT,
                                              unsigned short* __restrict__ cat) {
    __shared__ alignas(16) unsigned short Ks[KT * 64];     // [key][d] swizzled
    __shared__ alignas(16) unsigned short Vs[HD * 64];     // [d][key] swizzled
    __shared__ unsigned short Ps[4 * 16 * LDP];            // per-wave [q][key]
    int t = threadIdx.x;
    int bx = blockIdx.x;               // Q tile (64 rows)
    int bh = blockIdx.y;               // 0..31
    int b = bh >> 4, hh = bh & 15;
    int lane = t & 63, w = t >> 6;
    int ln = lane & 15, quad = lane >> 4;
    int ln7 = ln & 7;
    const unsigned short* hb = h + (size_t)b * LL * D1;
    const unsigned short* vtb = vT + ((size_t)(b * NH + hh) * HD) * LL;

    bf16x8 qf[2];
    {
        const unsigned short* qbase = hb + (size_t)(bx * 64 + w * 16) * D1 + hh * HD;
        #pragma unroll
        for (int ks = 0; ks < 2; ks++)
            qf[ks] = *(const bf16x8*)(qbase + (size_t)ln * D1 + ks * 32 + quad * 8);
    }

    f32x4 O[4];
    #pragma unroll
    for (int vn = 0; vn < 4; vn++) O[vn] = {0.f, 0.f, 0.f, 0.f};
    float m_ = -1e30f, l_ = 0.f;

    unsigned short* Psw = Ps + w * 16 * LDP;

    int srow = t >> 3;                 // 0..31
    int scg  = (t & 7) ^ (srow & 7);   // global chunk for this LDS slot

    for (int kb = 0; kb < LL / KT; kb++) {
        __syncthreads();
        {   // stage K tile [64 key][64 d] and V^T tile [64 d][64 key]
            const unsigned short* kb0 = hb + (size_t)(kb * KT) * D1 + HID + hh * HD;
            gl_lds16(kb0 + (size_t)srow * D1 + scg * 8,        &Ks[t * 8]);
            gl_lds16(kb0 + (size_t)(srow + 32) * D1 + scg * 8, &Ks[2048 + t * 8]);
            const unsigned short* vb0 = vtb + kb * KT;
            gl_lds16(vb0 + (size_t)srow * LL + scg * 8,        &Vs[t * 8]);
            gl_lds16(vb0 + (size_t)(srow + 32) * LL + scg * 8, &Vs[2048 + t * 8]);
        }
        __syncthreads();

        // S^T = K @ Q^T : D[row=key=kt*16+quad*4+r][col=q=ln]
        f32x4 st[4];
        #pragma unroll
        for (int kt = 0; kt < 4; kt++) {
            st[kt] = {0.f, 0.f, 0.f, 0.f};
            #pragma unroll
            for (int ks = 0; ks < 2; ks++) {
                bf16x8 kf = *(const bf16x8*)(&Ks[(kt * 16 + ln) * 64 + (((ks * 4 + quad) ^ ln7) * 8)]);
                st[kt] = __builtin_amdgcn_mfma_f32_16x16x32_bf16(kf, qf[ks], st[kt], 0, 0, 0);
            }
        }

        // online softmax (exp2 domain)
        {
            float p[16];
            float mx = -1e30f;
            #pragma unroll
            for (int kt = 0; kt < 4; kt++)
                #pragma unroll
                for (int r = 0; r < 4; r++) {
                    float v = st[kt][r];
                    p[kt * 4 + r] = v;
                    mx = fmaxf(mx, v);
                }
            mx = fmaxf(mx, __shfl_xor(mx, 16));
            mx = fmaxf(mx, __shfl_xor(mx, 32));
            float mnew = fmaxf(m_, mx);
            float alpha = __builtin_amdgcn_exp2f(m_ - mnew);
            m_ = mnew;
            float sum = 0.f;
            #pragma unroll
            for (int i = 0; i < 16; i++) {
                float e = __builtin_amdgcn_exp2f(p[i] - mnew);
                p[i] = e;
                sum += e;
            }
            sum += __shfl_xor(sum, 16);
            sum += __shfl_xor(sum, 32);
            l_ = l_ * alpha + sum;
            #pragma unroll
            for (int vn = 0; vn < 4; vn++)
                #pragma unroll
                for (int r = 0; r < 4; r++) O[vn][r] *= alpha;
            #pragma unroll
            for (int kt = 0; kt < 4; kt++) {
                unsigned long long pk =
                    (unsigned long long)pkbf2(p[kt*4+0], p[kt*4+1])
                  | ((unsigned long long)pkbf2(p[kt*4+2], p[kt*4+3]) << 32);
                *(unsigned long long*)(&Psw[ln * LDP + kt * 16 + quad * 4]) = pk;
            }
        }

        // O^T += V^T @ P^T
        #pragma unroll
        for (int kt2 = 0; kt2 < 2; kt2++) {
            bf16x8 pb = *(const bf16x8*)(&Psw[ln * LDP + kt2 * 32 + quad * 8]);
            #pragma unroll
            for (int vn = 0; vn < 4; vn++) {
                bf16x8 vf = *(const bf16x8*)(&Vs[(vn * 16 + ln) * 64 + (((kt2 * 4 + quad) ^ ln7) * 8)]);
                O[vn] = __builtin_amdgcn_mfma_f32_16x16x32_bf16(vf, pb, O[vn], 0, 0, 0);
            }
        }
    }

    // epilogue: O^T[d][q] / l -> cat[token][hh*64+d]
    {
        float rl = 1.0f / l_;
        size_t row = (size_t)(b * LL + bx * 64 + w * 16 + ln);
        #pragma unroll
        for (int vn = 0; vn < 4; vn++) {
            #pragma unroll
            for (int r2 = 0; r2 < 4; r2 += 2) {
                unsigned int pk = pkbf2(O[vn][r2] * rl, O[vn][r2 + 1] * rl);
                *(unsigned int*)(&cat[row * DCAT + hh * HD + vn * 16 + quad * 4 + r2]) = pk;
            }
        }
    }
}

// ---------------- host launch ----------------
extern "C" void kernel_launch(void* const* d_in, const int* in_sizes, int n_in,
                              void* d_out, int out_size, void* d_ws, size_t ws_size,
                              hipStream_t stream) {
    const float* x       = (const float*)d_in[0];
    const float* vec     = (const float*)d_in[1];
    const float* pe      = (const float*)d_in[2];
    const float* w_mod   = (const float*)d_in[3];
    const float* b_mod   = (const float*)d_in[4];
    const float* w1      = (const float*)d_in[5];
    const float* b1      = (const float*)d_in[6];
    const float* w_mlp   = (const float*)d_in[7];
    const float* b_mlp   = (const float*)d_in[8];
    const float* w2      = (const float*)d_in[9];
    const float* b2      = (const float*)d_in[10];
    const float* q_scale = (const float*)d_in[11];
    const float* k_scale = (const float*)d_in[12];
    float* out = (float*)d_out;

    char* ws = (char*)d_ws;
    size_t off = 0;
    float* mod = (float*)(ws + off);                     off += 6144 * 4;
    unsigned short* xmod  = (unsigned short*)(ws + off); off += (size_t)TOK * HID * 2;
    unsigned short* h     = (unsigned short*)(ws + off); off += (size_t)TOK * D1 * 2;
    unsigned short* cat   = (unsigned short*)(ws + off); off += (size_t)TOK * DCAT * 2;
    unsigned short* w1T   = (unsigned short*)(ws + off); off += (size_t)D1 * HID * 2;
    unsigned short* wmlpT = (unsigned short*)(ws + off); off += (size_t)HID * MLP * 2;
    unsigned short* w2T   = (unsigned short*)(ws + off); off += (size_t)HID * DCAT * 2;
    unsigned short* vTr   = (unsigned short*)(ws + off); off += (size_t)BB * NH * HD * LL * 2;
    float* part = (float*)(ws + off);                    off += (size_t)2 * TOK * HID * 4;

    k_transpose_cvt<<<dim3(D1 / 32, HID / 32), dim3(32, 8), 0, stream>>>(w1, w1T, HID, D1);
    k_transpose_cvt<<<dim3(HID / 32, MLP / 32), dim3(32, 8), 0, stream>>>(w_mlp, wmlpT, MLP, HID);
    k_transpose_cvt<<<dim3(HID / 32, DCAT / 32), dim3(32, 8), 0, stream>>>(w2, w2T, DCAT, HID);

    k_mod<<<dim3(96, BB), 256, 0, stream>>>(vec, w_mod, b_mod, mod);
    k_lnmod<<<TOK, 256, 0, stream>>>(x, mod, xmod);

    // h = x_mod @ w1 + b1 with fused RMSNorm+RoPE (q,k) and transposed-V store
    k_gemm<4><<<dim3(TOK / 128, D1 / 128), 256, 0, stream>>>(
        xmod, HID, w1T, HID, b1, h, nullptr, D1, HID, nullptr, nullptr,
        vTr, pe, q_scale, k_scale);

    k_attn<<<dim3(LL / 64, BB * NH), 256, 0, stream>>>(h, vTr, cat);

    // mlp partials: h_mlp @ w_mlp   (M=4096, N=1024, K=4096, split-K=2)
    k_gemm<3><<<dim3(TOK / 128, HID / 128, 2), 256, 0, stream>>>(
        h + DQKV, D1, wmlpT, MLP, b_mlp, nullptr, part, HID, MLP, nullptr, nullptr,
        nullptr, nullptr, nullptr, nullptr);
    k_red1<<<TOK * HID / 1024, 256, 0, stream>>>(part, b_mlp, cat);

    // out partials: cat @ w2   (M=4096, N=1024, K=2048, split-K=2)
    k_gemm<3><<<dim3(TOK / 128, HID / 128, 2), 256, 0, stream>>>(
        cat, DCAT, w2T, DCAT, b2, nullptr, part, HID, DCAT, nullptr, nullptr,
        nullptr, nullptr, nullptr, nullptr);
    k_red2<<<TOK * HID / 1024, 256, 0, stream>>>(part, b2, x, mod, out);
}